// Round 11
// baseline (570.382 us; speedup 1.0000x reference)
//
#include <hip/hip_runtime.h>
#include <math.h>

#define NTOK   262144
#define DIM    1024
#define NEXP   64
#define TOPK   8
#define ROWS   16            // rows per block (one 16-row m-tile)
#define BLK    256           // 4 waves; wave w owns K-quarter w (256 floats)

#define OFF_IDX ((size_t)NTOK * TOPK)
#define OFF_USE (2 * (size_t)NTOK * TOPK)
#define OFF_TOT (OFF_USE + NEXP)

typedef __attribute__((ext_vector_type(8))) short bf16x8;
typedef __attribute__((ext_vector_type(4))) float f32x4;

union FragU { bf16x8 v; unsigned int u[4]; };

// pack 8 f32 (a=k0..3, b=k4..7) -> bf16x8 fragment (truncate)
__device__ __forceinline__ bf16x8 pack_bf16(float4 a, float4 b) {
    FragU r;
    r.u[0] = (__float_as_uint(a.x) >> 16) | (__float_as_uint(a.y) & 0xFFFF0000u);
    r.u[1] = (__float_as_uint(a.z) >> 16) | (__float_as_uint(a.w) & 0xFFFF0000u);
    r.u[2] = (__float_as_uint(b.x) >> 16) | (__float_as_uint(b.y) & 0xFFFF0000u);
    r.u[3] = (__float_as_uint(b.z) >> 16) | (__float_as_uint(b.w) & 0xFFFF0000u);
    return r.v;
}

// W [64][1024] f32 -> bf16 MFMA B-fragments in d_ws:
//   wf[((kc*4+nt)*64 + lane)*8 + j] = bf16(W[nt*16+(lane&15)][kc*32+(lane>>4)*8+j])
// kc = global K-step 0..31. Also init usage counters + total_tokens.
__global__ __launch_bounds__(256) void gate_prep_kernel(const float* __restrict__ W,
                                                        unsigned short* __restrict__ wf,
                                                        float* __restrict__ out) {
    int idx = blockIdx.x * 256 + threadIdx.x;      // 65536 total
    int j    = idx & 7;
    int lane = (idx >> 3) & 63;
    int nt   = (idx >> 9) & 3;
    int kc   = idx >> 11;
    int fq = lane >> 4, fr = lane & 15;
    float v = W[(size_t)(nt * 16 + fr) * DIM + kc * 32 + fq * 8 + j];
    unsigned int u = __float_as_uint(v);
    u += 0x7FFFu + ((u >> 16) & 1u);               // RNE to bf16
    wf[idx] = (unsigned short)(u >> 16);

    if (blockIdx.x == 0) {
        if (threadIdx.x < NEXP) out[OFF_USE + threadIdx.x] = 0.0f;
        if (threadIdx.x == NEXP) out[OFF_TOT] = (float)((size_t)NTOK * TOPK);
    }
}

__global__ __launch_bounds__(BLK, 2) void gate_kernel(const float* __restrict__ x,
                                                      const unsigned short* __restrict__ wf,
                                                      const float* __restrict__ bias,
                                                      float* __restrict__ out) {
    // Block = 16 rows (64 KB contiguous x region). Wave w stages rows 0..15 x
    // its own 1KB row-quarter (16 fully-contiguous 1KB bursts) into a private
    // 16KB slice, computes its K-quarter partial, then a short barrier epilogue
    // reduces partials. LDS: x 64KB; part[4][16][64] & scores[16][65] alias
    // into the dead x region after the compute barrier.
    __shared__ __align__(16) char smem[65536];
    __shared__ float hist[NEXP];

    const int tid  = threadIdx.x;
    const int w    = tid >> 6;
    const int lane = tid & 63;
    const int fq   = lane >> 4;   // 0..3
    const int fr   = lane & 15;   // 0..15
    const size_t rowBase = (size_t)blockIdx.x * ROWS;

    if (tid < NEXP) hist[tid] = 0.0f;

    // ---- B fragments for this wave's K-quarter (kc = w*8 + j), L2-resident
    const bf16x8* wfv = (const bf16x8*)wf;
    bf16x8 bfrag[32];
#pragma unroll
    for (int j = 0; j < 8; j++)
#pragma unroll
        for (int nt = 0; nt < 4; nt++)
            bfrag[j * 4 + nt] = wfv[(size_t)((w * 8 + j) * 4 + nt) * 64 + lane];
    __builtin_amdgcn_sched_barrier(0);

    // ---- stage: instr i = row i, quarter w: ONE contiguous 1KB burst.
    // Source pre-swizzled within the 1KB (unit l -> l ^ (row&7)) so the linear
    // LDS dest yields the bank-swizzled layout (both-sides-or-neither rule).
    const char* xb = (const char*)(x + rowBase * DIM);
#pragma unroll
    for (int i = 0; i < 16; i++) {
        const char* s = xb + (size_t)i * 4096 + (size_t)w * 1024
                        + ((lane ^ (i & 7)) * 16);
        __builtin_amdgcn_global_load_lds(
            (const __attribute__((address_space(1))) unsigned int*)s,
            (__attribute__((address_space(3))) unsigned int*)(smem + w * 16384 + i * 1024),
            16, 0, 2 /* NT streaming read */);
    }
    asm volatile("s_waitcnt vmcnt(0)" ::: "memory");
    __builtin_amdgcn_sched_barrier(0);

    // ---- compute own K-quarter: 8 k-steps x 4 nt MFMA.
    // LDS slice layout: [16 rows][64 units of 16B]; LDS(row, l) = x unit
    // (l ^ (row&7)) of quarter w -> read local unit u at (u ^ (fr&7)).
    const float4* xt = (const float4*)(smem + w * 16384);
    f32x4 acc[4] = {};
#pragma unroll
    for (int j = 0; j < 8; j++) {
        int u0 = j * 8 + fq * 2;
        bf16x8 af = pack_bf16(xt[fr * 64 + (u0 ^ (fr & 7))],
                              xt[fr * 64 + ((u0 + 1) ^ (fr & 7))]);
#pragma unroll
        for (int nt = 0; nt < 4; nt++)
            acc[nt] = __builtin_amdgcn_mfma_f32_16x16x32_bf16(af, bfrag[j * 4 + nt], acc[nt], 0, 0, 0);
    }
    __syncthreads();   // all compute done -> x region dead

    // ---- partial C -> LDS part[4][16][64] f32 at smem+0.
    // C/D layout: col = fr, row = fq*4 + r.
    float* part = (float*)smem;
#pragma unroll
    for (int nt = 0; nt < 4; nt++)
#pragma unroll
        for (int r = 0; r < 4; r++)
            part[w * 1024 + (fq * 4 + r) * 64 + nt * 16 + fr] = acc[nt][r];
    __syncthreads();

    // ---- reduce partials + bias -> scores [16][65] f32 at smem+16384
    float* scores = (float*)(smem + 16384);
#pragma unroll
    for (int it = 0; it < 4; it++) {
        int idx = tid + it * 256;          // 1024 outputs
        int e = idx & 63, r = idx >> 6;
        float s = bias[e] + part[r * 64 + e] + part[1024 + r * 64 + e]
                + part[2048 + r * 64 + e] + part[3072 + r * 64 + e];
        scores[r * 65 + e] = s;
    }
    __syncthreads();

    // ---- epilogue: one thread per row (threads 0..15)
    if (tid < ROWS) {
        const float* rp = scores + tid * 65;

        // top-8 on RAW scores (exp monotone; strict > keeps ascending index
        // order among ties, matching lax.top_k)
        float tv[8]; int ti[8];
#pragma unroll
        for (int k = 0; k < 8; k++) { tv[k] = -1e30f; ti[k] = 0; }

#pragma unroll 4
        for (int e = 0; e < NEXP; e++) {
            float s = rp[e];
#pragma unroll
            for (int k = 7; k >= 1; k--) {
                bool up   = s > tv[k - 1];
                bool here = s > tv[k];
                float nv = up ? tv[k - 1] : (here ? s : tv[k]);
                int   ni = up ? ti[k - 1] : (here ? e : ti[k]);
                tv[k] = nv; ti[k] = ni;
            }
            bool c0 = s > tv[0];
            ti[0] = c0 ? e : ti[0];
            tv[0] = c0 ? s : tv[0];
        }
        float m = tv[0];   // row max

        float sum = 0.0f;
#pragma unroll 8
        for (int e = 0; e < NEXP; e++) sum += __expf(rp[e] - m);
        float rinv = 1.0f / sum;

        float wv_[8];
#pragma unroll
        for (int k = 0; k < 8; k++) wv_[k] = __expf(tv[k] - m) * rinv;

        size_t ro = (rowBase + tid) * TOPK;
        *(float4*)(out + ro)     = make_float4(wv_[0], wv_[1], wv_[2], wv_[3]);
        *(float4*)(out + ro + 4) = make_float4(wv_[4], wv_[5], wv_[6], wv_[7]);
        *(float4*)(out + OFF_IDX + ro)     = make_float4((float)ti[0], (float)ti[1], (float)ti[2], (float)ti[3]);
        *(float4*)(out + OFF_IDX + ro + 4) = make_float4((float)ti[4], (float)ti[5], (float)ti[6], (float)ti[7]);
#pragma unroll
        for (int k = 0; k < 8; k++) atomicAdd(&hist[ti[k]], 1.0f);
    }
    __syncthreads();
    if (tid < NEXP) atomicAdd(&out[OFF_USE + tid], hist[tid]);
}

extern "C" void kernel_launch(void* const* d_in, const int* in_sizes, int n_in,
                              void* d_out, int out_size, void* d_ws, size_t ws_size,
                              hipStream_t stream) {
    const float* x    = (const float*)d_in[0];
    const float* W    = (const float*)d_in[1];
    const float* bias = (const float*)d_in[2];
    float* out = (float*)d_out;
    unsigned short* wf = (unsigned short*)d_ws;   // 128 KB fragment-ordered bf16 W

    gate_prep_kernel<<<256, 256, 0, stream>>>(W, wf, out);
    gate_kernel<<<NTOK / ROWS, BLK, 0, stream>>>(x, wf, bias, out);
}

// Round 12
// 220.065 us; speedup vs baseline: 2.5919x; 2.5919x over previous
//
#include <hip/hip_runtime.h>
#include <math.h>

#define NTOK   262144
#define DIM    1024
#define NEXP   64
#define TOPK   8
#define WROWS  32           // rows per wave (2 m-tiles)
#define ROWS   128          // rows per block = 4 waves x 32 rows
#define BLK    256
#define BK     32           // K-chunk (floats) = 128 B per row
#define NKC    (DIM / BK)   // 32 K-steps
#define BUFSZ  4096         // 32 rows x 128 B
#define SLICE  (3 * BUFSZ)  // per-wave: TRIPLE-buffered stage; scores [32][65] alias

#define OFF_IDX ((size_t)NTOK * TOPK)
#define OFF_USE (2 * (size_t)NTOK * TOPK)
#define OFF_TOT (OFF_USE + NEXP)

typedef __attribute__((ext_vector_type(8))) short bf16x8;
typedef __attribute__((ext_vector_type(4))) float f32x4;

union FragU { bf16x8 v; unsigned int u[4]; };

// pack 8 f32 (a=k0..3, b=k4..7) -> bf16x8 fragment (truncate)
__device__ __forceinline__ bf16x8 pack_bf16(float4 a, float4 b) {
    FragU r;
    r.u[0] = (__float_as_uint(a.x) >> 16) | (__float_as_uint(a.y) & 0xFFFF0000u);
    r.u[1] = (__float_as_uint(a.z) >> 16) | (__float_as_uint(a.w) & 0xFFFF0000u);
    r.u[2] = (__float_as_uint(b.x) >> 16) | (__float_as_uint(b.y) & 0xFFFF0000u);
    r.u[3] = (__float_as_uint(b.z) >> 16) | (__float_as_uint(b.w) & 0xFFFF0000u);
    return r.v;
}

// W [64][1024] f32 -> bf16 MFMA B-fragments in d_ws:
//   wf[((kc*4+nt)*64 + lane)*8 + j] = bf16(W[nt*16+(lane&15)][kc*32+(lane>>4)*8+j])
// Also init usage counters + total_tokens.
__global__ __launch_bounds__(256) void gate_prep_kernel(const float* __restrict__ W,
                                                        unsigned short* __restrict__ wf,
                                                        float* __restrict__ out) {
    int idx = blockIdx.x * 256 + threadIdx.x;      // 65536 total
    int j    = idx & 7;
    int lane = (idx >> 3) & 63;
    int nt   = (idx >> 9) & 3;
    int kc   = idx >> 11;
    int fq = lane >> 4, fr = lane & 15;
    float v = W[(size_t)(nt * 16 + fr) * DIM + kc * BK + fq * 8 + j];
    unsigned int u = __float_as_uint(v);
    u += 0x7FFFu + ((u >> 16) & 1u);               // RNE to bf16
    wf[idx] = (unsigned short)(u >> 16);

    if (blockIdx.x == 0) {
        if (threadIdx.x < NEXP) out[OFF_USE + threadIdx.x] = 0.0f;
        if (threadIdx.x == NEXP) out[OFF_TOT] = (float)((size_t)NTOK * TOPK);
    }
}

__global__ __launch_bounds__(BLK, 3) void gate_kernel(const float* __restrict__ x,
                                                      const unsigned short* __restrict__ wf,
                                                      const float* __restrict__ bias,
                                                      float* __restrict__ out) {
    // r9 structure: per-wave private slices, NO barriers in the K-loop, counted
    // vmcnt, depth-2 stage pipeline (triple buffer), NT staging loads, K-phase
    // rotation. ONE change vs r9: rotation is BLOCK-uniform (kc0 = block&31,
    // no per-wave term) -> all 4 waves request the same 4KB wf window per step
    // and L1 serves ~3 of 4 (wf L2 traffic ~4x down), while 2048 blocks still
    // spread the in-flight kc*128 offsets uniformly over all 32 channel phases.
    __shared__ __align__(16) char smem[4 * SLICE];
    __shared__ float hist[NEXP];

    const int tid  = threadIdx.x;
    const int w    = tid >> 6;
    const int lane = tid & 63;
    const int fq   = lane >> 4;   // 0..3
    const int fr   = lane & 15;   // 0..15
    const size_t rowBase = (size_t)blockIdx.x * ROWS;

    if (tid < NEXP) hist[tid] = 0.0f;

    char* myslice = smem + w * SLICE;

    // Staging: 32 rows x 128 B per buffer (4 KB), 4 instrs x 1 KB.
    // Instr i, lane l: flat = i*64+l; row = flat>>3 (0..31), phys 16B-unit
    // p = flat&7; SOURCE pre-swizzled (u = p ^ (row&7)) so the linear LDS
    // dest yields the swizzled layout (both-sides-or-neither rule).
    const char* xb = (const char*)(x + (rowBase + (size_t)w * WROWS) * DIM);
    const char* src[4];
#pragma unroll
    for (int i = 0; i < 4; i++) {
        int flat = i * 64 + lane;
        int row = flat >> 3;
        int u = (flat & 7) ^ (row & 7);
        src[i] = xb + (size_t)row * (DIM * 4) + u * 16;
    }

#define STAGE(BUF, kc)                                                            \
    do {                                                                          \
        _Pragma("unroll")                                                         \
        for (int i_ = 0; i_ < 4; i_++)                                            \
            __builtin_amdgcn_global_load_lds(                                     \
                (const __attribute__((address_space(1))) unsigned int*)(src[i_] + (size_t)(kc) * 128), \
                (__attribute__((address_space(3))) unsigned int*)(myslice + (BUF) * BUFSZ + i_ * 1024), \
                16, 0, 2 /* NT: non-temporal streaming read */);                  \
    } while (0)

    // A-fragment ds_read slot indices (16B units within a 4KB buffer):
    // m-tile mt, half h: row = mt*16+fr, unit = (fq*2+h) ^ (fr&7)
    int aslot[2][2];
#pragma unroll
    for (int mt = 0; mt < 2; mt++)
#pragma unroll
        for (int h = 0; h < 2; h++)
            aslot[mt][h] = (mt * 16 + fr) * 8 + (((fq * 2 + h) ^ fr) & 7);

    const bf16x8* wfv = (const bf16x8*)wf;

    f32x4 acc[2][4] = {};   // [mt][nt]
    bf16x8 bcur[4];

    // K-phase rotation start: BLOCK-uniform (the one change vs r9)
    const int kc0 = (int)blockIdx.x & 31;

    // Prologue FIFO: bfrag(kc0) [4] | stage(kc0) [4] | stage(kc0+1) [4] -> 12 outstanding
#pragma unroll
    for (int nt = 0; nt < 4; nt++) bcur[nt] = wfv[(size_t)(kc0 * 4 + nt) * 64 + lane];
    __builtin_amdgcn_sched_barrier(0);
    STAGE(0, kc0);
    STAGE(1, (kc0 + 1) & 31);

    // Step: issue bfrag(next) FIRST (L1/L2-fast), then stage(+2); then wait
    // vmcnt(12) -> completes exactly [bfrag(cur), stage(cur)] (stage issued
    // two steps ago: depth 2). Never drains to 0 in-loop.
#define GSTEP(KC, BUF, SBUF, MODE)                                               \
    {                                                                             \
        const int kc_ = (KC);                                                     \
        bf16x8 bnext[4];                                                          \
        if ((MODE) >= 1) {                                                        \
            const int kn_ = (kc_ + 1) & 31;                                       \
            _Pragma("unroll")                                                     \
            for (int nt = 0; nt < 4; nt++)                                        \
                bnext[nt] = wfv[(size_t)(kn_ * 4 + nt) * 64 + lane];              \
            __builtin_amdgcn_sched_barrier(0);                                    \
        }                                                                         \
        if ((MODE) == 2) STAGE(SBUF, (kc_ + 2) & 31);                             \
        if ((MODE) == 2)      asm volatile("s_waitcnt vmcnt(12)" ::: "memory");   \
        else if ((MODE) == 1) asm volatile("s_waitcnt vmcnt(8)" ::: "memory");    \
        else                  asm volatile("s_waitcnt vmcnt(0)" ::: "memory");    \
        __builtin_amdgcn_sched_barrier(0);                                        \
        const float4* xt = (const float4*)(myslice + (BUF) * BUFSZ);              \
        _Pragma("unroll")                                                         \
        for (int mt = 0; mt < 2; mt++) {                                          \
            bf16x8 af = pack_bf16(xt[aslot[mt][0]], xt[aslot[mt][1]]);            \
            _Pragma("unroll")                                                     \
            for (int nt = 0; nt < 4; nt++)                                        \
                acc[mt][nt] = __builtin_amdgcn_mfma_f32_16x16x32_bf16(af, bcur[nt], acc[mt][nt], 0, 0, 0); \
        }                                                                         \
        if ((MODE) >= 1) {                                                        \
            _Pragma("unroll")                                                     \
            for (int nt = 0; nt < 4; nt++) bcur[nt] = bnext[nt];                  \
        }                                                                         \
    }

#pragma unroll 1
    for (int t = 0; t < 10; t++) {            // steps 0..29, buf = t%3
        GSTEP((kc0 + 3 * t) & 31,     0, 2, 2);
        GSTEP((kc0 + 3 * t + 1) & 31, 1, 0, 2);
        GSTEP((kc0 + 3 * t + 2) & 31, 2, 1, 2);
    }
    GSTEP((kc0 + 30) & 31, 0, 0, 1);          // waits [bfrag, stage] of step 30
    GSTEP((kc0 + 31) & 31, 1, 0, 0);          // drains

    // scores (+bias) -> own slice, [32 rows][65] f32 (aliases own stage bufs;
    // own DMA done via final vmcnt(0)).  C/D layout: col = fr, row = fq*4 + r.
    float* sw = (float*)myslice;
    float bv[4];
#pragma unroll
    for (int nt = 0; nt < 4; nt++) bv[nt] = bias[nt * 16 + fr];
#pragma unroll
    for (int mt = 0; mt < 2; mt++) {
        int mbase = mt * 16 + fq * 4;
#pragma unroll
        for (int nt = 0; nt < 4; nt++) {
            int n = nt * 16 + fr;
#pragma unroll
            for (int r = 0; r < 4; r++)
                sw[(mbase + r) * 65 + n] = acc[mt][nt][r] + bv[nt];
        }
    }
    __syncthreads();   // the only block-wide barrier

    // epilogue: one thread per row (threads 0..127)
    if (tid < ROWS) {
        const float* rp = (const float*)(smem + (tid >> 5) * SLICE) + (tid & 31) * 65;

        // top-8 on RAW scores (exp monotone; strict > keeps ascending index
        // order among ties, matching lax.top_k)
        float tv[8]; int ti[8];
#pragma unroll
        for (int k = 0; k < 8; k++) { tv[k] = -1e30f; ti[k] = 0; }

#pragma unroll 4
        for (int e = 0; e < NEXP; e++) {
            float s = rp[e];
#pragma unroll
            for (int k = 7; k >= 1; k--) {
                bool up   = s > tv[k - 1];
                bool here = s > tv[k];
                float nv = up ? tv[k - 1] : (here ? s : tv[k]);
                int   ni = up ? ti[k - 1] : (here ? e : ti[k]);
                tv[k] = nv; ti[k] = ni;
            }
            bool c0 = s > tv[0];
            ti[0] = c0 ? e : ti[0];
            tv[0] = c0 ? s : tv[0];
        }
        float m = tv[0];   // row max

        float sum = 0.0f;
#pragma unroll 8
        for (int e = 0; e < NEXP; e++) sum += __expf(rp[e] - m);
        float rinv = 1.0f / sum;

        float wv_[8];
#pragma unroll
        for (int k = 0; k < 8; k++) wv_[k] = __expf(tv[k] - m) * rinv;

        size_t ro = (rowBase + tid) * TOPK;
        *(float4*)(out + ro)     = make_float4(wv_[0], wv_[1], wv_[2], wv_[3]);
        *(float4*)(out + ro + 4) = make_float4(wv_[4], wv_[5], wv_[6], wv_[7]);
        *(float4*)(out + OFF_IDX + ro)     = make_float4((float)ti[0], (float)ti[1], (float)ti[2], (float)ti[3]);
        *(float4*)(out + OFF_IDX + ro + 4) = make_float4((float)ti[4], (float)ti[5], (float)ti[6], (float)ti[7]);
#pragma unroll
        for (int k = 0; k < 8; k++) atomicAdd(&hist[ti[k]], 1.0f);
    }
    __syncthreads();
    if (tid < NEXP) atomicAdd(&out[OFF_USE + tid], hist[tid]);
}

extern "C" void kernel_launch(void* const* d_in, const int* in_sizes, int n_in,
                              void* d_out, int out_size, void* d_ws, size_t ws_size,
                              hipStream_t stream) {
    const float* x    = (const float*)d_in[0];
    const float* W    = (const float*)d_in[1];
    const float* bias = (const float*)d_in[2];
    float* out = (float*)d_out;
    unsigned short* wf = (unsigned short*)d_ws;   // 128 KB fragment-ordered bf16 W

    gate_prep_kernel<<<256, 256, 0, stream>>>(W, wf, out);
    gate_kernel<<<NTOK / ROWS, BLK, 0, stream>>>(x, wf, bias, out);
}